// Round 6
// baseline (789.309 us; speedup 1.0000x reference)
//
#include <hip/hip_runtime.h>

#define NB 512
#define NC 32
#define NT 8192
#define TP 1024        // NT / 8 pooled windows
#define NG 11
#define WIN 128        // pooled windows per block (1024 samples, 4 KB/channel)
#define NTB (TP/WIN)   // 8 time-tiles per batch

typedef float f32x4 __attribute__((ext_vector_type(4)));

// DENSE lane mapping: load l, lane i covers bytes [1024*l + 16*i, +16) of the
// tile -> every 64-B line touched by exactly one instruction, 1 KB/instr.
// Lane i owns QUAD 64l+i (half of window 32l + i/2); pairing deferred to the
// epilogue via shfl_xor(1).
//
// DO_CH2: two channels batched. All 8 x-loads (nt) issue before any consuming
// VALU -> 8 KB/wave in flight. Peak live ~70 VGPR: requires the 128-VGPR
// budget pinned by amdgpu_waves_per_eu(4,4). (R3 post-mortem: the RA squeezed
// a ~100-reg demand into 64 VGPRs to chase 8 waves/EU and spilled 705 MB to
// scratch; pinning the occupancy target removes that incentive.)

template<int C>
__device__ __forceinline__ void ld_x(const float* __restrict__ xb, f32x4 (&dst)[4])
{
    #pragma unroll
    for (int l = 0; l < 4; ++l)
        dst[l] = __builtin_nontemporal_load((const f32x4*)(xb + C * NT + 256 * l));
}

template<int C>
__device__ __forceinline__ void comp_ch(const float* __restrict__ Wb,
                                        const float* __restrict__ bias,
                                        const f32x4 (&xv)[4], float (&acc)[4])
{
    f32x4 wv[4];
    #pragma unroll
    for (int l = 0; l < 4; ++l)
        wv[l] = *(const f32x4*)(Wb + C * NT + 256 * l);
    const float nbc = -bias[C];
    #pragma unroll
    for (int l = 0; l < 4; ++l) {
        const f32x4 a = xv[l], b = wv[l];
        float s;
        s  = fmaxf(fmaf(a.x, b.x, nbc), 0.0f);
        s += fmaxf(fmaf(a.y, b.y, nbc), 0.0f);
        s += fmaxf(fmaf(a.z, b.z, nbc), 0.0f);
        s += fmaxf(fmaf(a.w, b.w, nbc), 0.0f);
        acc[l] += s;
    }
}

// Two channels: 8 x-loads up front, W loads interleaved with compute.
#define DO_CH2(c0, g0, c1, g1) do {                                           \
    f32x4 xv0[4], xv1[4];                                                     \
    ld_x<c0>(xb, xv0);                                                        \
    ld_x<c1>(xb, xv1);                                                        \
    comp_ch<c0>(Wb, bias, xv0, acc[g0]);                                      \
    comp_ch<c1>(Wb, bias, xv1, acc[g1]);                                      \
} while (0)

#define DO_CH1(c0, g0) do {                                                   \
    f32x4 xv0[4];                                                             \
    ld_x<c0>(xb, xv0);                                                        \
    comp_ch<c0>(Wb, bias, xv0, acc[g0]);                                      \
} while (0)

// Lanes 2j,2j+1 hold the two quads of window 32l+j; after shfl_xor(1) both
// hold the window sum; even lanes store 32 consecutive dwords (128 B
// coalesced full-line store).
__device__ __forceinline__ void store_g(float* __restrict__ ob, int gid,
                                        float inv, const float (&acc)[4], int lane)
{
    #pragma unroll
    for (int l = 0; l < 4; ++l) {
        const float s = acc[l] + __shfl_xor(acc[l], 1, 64);
        if (!(lane & 1))
            __builtin_nontemporal_store(s * inv,
                ob + (size_t)gid * TP + 32 * l + (lane >> 1));
    }
}

__global__ __launch_bounds__(256)
__attribute__((amdgpu_waves_per_eu(4, 4)))
void local_gnn_kernel(
    const float* __restrict__ xg,
    const float* __restrict__ W,
    const float* __restrict__ bias,
    float* __restrict__ out)
{
    const int lane = threadIdx.x & 63;
    const int y    = threadIdx.x >> 6;     // wave id — wave-uniform
    const int bb   = blockIdx.x >> 3;      // batch
    const int tb   = blockIdx.x & 7;       // time-tile

    const float* xb = xg + (size_t)bb * (NC * NT) + tb * (WIN * 8) + 4 * lane;
    const float* Wb = W + tb * (WIN * 8) + 4 * lane;

    // acc[lg][l]: local group lg (<=3 per wave), quad-position l (4 per tile)
    float acc[3][4];
    #pragma unroll
    for (int lg = 0; lg < 3; ++lg)
        #pragma unroll
        for (int l = 0; l < 4; ++l) acc[lg][l] = 0.0f;

    float* ob = out + (size_t)bb * (NG * TP) + tb * WIN;

    // Each wave owns WHOLE groups -> no cross-wave reduction, no LDS, no
    // barrier. Channel counts per wave: 7 / 7 / 7 / 8.
    switch (y) {
    case 0:  // g0:{0,1}  g1:{3,2}  g6:{6,23,24}
        DO_CH2(0, 0, 1, 0);
        DO_CH2(2, 1, 3, 1);
        DO_CH2(6, 2, 23, 2);
        DO_CH1(24, 2);
        store_g(ob, 0, 1.f/16, acc[0], lane);
        store_g(ob, 1, 1.f/16, acc[1], lane);
        store_g(ob, 6, 1.f/24, acc[2], lane);
        break;
    case 1:  // g2:{4,5}  g7:{8,9,27}  g9:{12,30}
        DO_CH2(4, 0, 5, 0);
        DO_CH2(8, 1, 9, 1);
        DO_CH2(27, 1, 12, 2);
        DO_CH1(30, 2);
        store_g(ob, 2, 1.f/16, acc[0], lane);
        store_g(ob, 7, 1.f/24, acc[1], lane);
        store_g(ob, 9, 1.f/16, acc[2], lane);
        break;
    case 2:  // g3:{16,17}  g4:{19,20}  g10:{13,14,31}
        DO_CH2(16, 0, 17, 0);
        DO_CH2(19, 1, 20, 1);
        DO_CH2(13, 2, 14, 2);
        DO_CH1(31, 2);
        store_g(ob, 3, 1.f/16, acc[0], lane);
        store_g(ob, 4, 1.f/16, acc[1], lane);
        store_g(ob, 10, 1.f/24, acc[2], lane);
        break;
    default: // g5:{22,21}  g8:{11,10,15,28,26,29}
        DO_CH2(21, 0, 22, 0);
        DO_CH2(10, 1, 11, 1);
        DO_CH2(15, 1, 26, 1);
        DO_CH2(28, 1, 29, 1);
        store_g(ob, 5, 1.f/16, acc[0], lane);
        store_g(ob, 8, 1.f/48, acc[1], lane);
        break;
    }
}

extern "C" void kernel_launch(void* const* d_in, const int* in_sizes, int n_in,
                              void* d_out, int out_size, void* d_ws, size_t ws_size,
                              hipStream_t stream) {
    const float* x    = (const float*)d_in[0];
    const float* W    = (const float*)d_in[1];
    const float* bias = (const float*)d_in[2];
    float* out        = (float*)d_out;

    const int grid = NB * NTB;   // 512 * 8 = 4096 blocks
    hipLaunchKernelGGL(local_gnn_kernel, dim3(grid), dim3(256), 0, stream,
                       x, W, bias, out);
}